// Round 2
// baseline (133.419 us; speedup 1.0000x reference)
//
#include <hip/hip_runtime.h>

#define SEQ 4096
#define DIM 1024
#define MD 64
#define TOPK 16
#define WPB 4                 // waves per block
#define RPB WPB               // 1 row per wave -> 16 KB LDS @ 256 threads

typedef float nfloat4 __attribute__((ext_vector_type(4)));  // native vec for nt ld/st

// R7b: register-resident epilogue + full occupancy (R7 with nt-load type fix).
//   out[d] = x[d] + signs[d] * w[inv_perm[d] & 63]
// where w = 1024^-0.5 * H64(zs). The linear x chunk stays in the lane's own
// registers from phase 1 (the old LDS scatter/readback recomputed exactly what
// this lane already held), and w is one scalar per lane, so w[bin] is a single
// ds_bpermute (conflict-free crossbar) with bin from the L2-hot inv_perm table.
// Phase-4 LDS traffic: 0 ops (was 32 conflicted ds_write_b32 + 8 ds_read_b128).
// RPW=1/WPB=4 keeps 16 KB LDS per 256-thread block -> 8 blocks/CU -> 32 waves/CU
// (was 20, LDS-capped); VGPRs freed by dropping pk[]/ya[]/yb[] pay for xs[4].
__global__ __launch_bounds__(WPB * 64) void csa_kernel(
    const float* __restrict__ x,
    const float* __restrict__ gates,
    const float* __restrict__ alpha,
    const float* __restrict__ tau,
    const float* __restrict__ signs,
    const int*   __restrict__ perm,
    const int*   __restrict__ inv_perm,
    const int*   __restrict__ target_idx,
    float*       __restrict__ out)
{
    __shared__ float y[RPB][DIM];

    const int lane = threadIdx.x & 63;
    const int wv   = threadIdx.x >> 6;
    const int r    = blockIdx.x * WPB + wv;   // one row per wave
    const int b    = r >> 12;                 // SEQ = 4096

    float* yr = y[wv];
    const nfloat4* xrow = (const nfloat4*)(x + (size_t)r * DIM);

    // ---- Phase 1: coalesced nt loads; keep x in regs; y = x*signs -> LDS.
    // Row is wave-private: no barrier, only lgkmcnt (compiler-inserted).
    nfloat4 xs[4];
    #pragma unroll
    for (int c = 0; c < 4; ++c) {
        xs[c] = __builtin_nontemporal_load(&xrow[c * 64 + lane]);
        const float4 sg = ((const float4*)signs)[c * 64 + lane];
        float4 a;
        a.x = xs[c].x * sg.x; a.y = xs[c].y * sg.y;
        a.z = xs[c].z * sg.z; a.w = xs[c].w * sg.w;
        ((float4*)yr)[c * 64 + lane] = a;
    }

    // ---- Phase 2: fold 1024 -> 64 bins (element perm[lane+64k] has bin lane)
    float s = 0.f;
    #pragma unroll
    for (int k = 0; k < 16; ++k) {
        const int p = perm[lane + 64 * k];    // coalesced, L1-hot (4 KB table)
        s += yr[p];                           // random ds_read_b32 (~2x conflict)
    }

    // ---- Phase 3a: 64-pt Hadamard (butterfly over lanes)
    float v = s;
    #pragma unroll
    for (int bit = 1; bit < MD; bit <<= 1) {
        const float o = __shfl_xor(v, bit, 64);
        v = (lane & bit) ? (o - v) : (v + o);
    }

    const int   ti   = target_idx[0];         // NT == 1
    const float gate = gates[(b + ti) * MD + lane];
    const float tauv = fabsf(tau[b + ti]);
    const float al   = alpha[b + ti];

    const float g  = gate * v * 0.03125f;     // 1024^-0.5
    const float ag = fabsf(g);

    // ---- Phase 3b: exact top-16 via bitwise binary search;
    // ties -> lowest lane (matches jax.lax.top_k)
    const unsigned ka = __float_as_uint(ag);
    unsigned T = 0u;
    #pragma unroll
    for (int bit = 30; bit >= 0; --bit) {
        const unsigned cand = T | (1u << bit);
        if (__popcll(__ballot(ka >= cand)) >= TOPK) T = cand;
    }
    const int ngt = __popcll(__ballot(ka > T));
    const unsigned long long lm = (1ull << lane) - 1ull;
    const int er = __popcll(__ballot(ka == T) & lm);
    const bool keep = (ka > T) || ((ka == T) && (er < TOPK - ngt));

    float zs = (keep && ag >= tauv) ? al * g : 0.f;

    // ---- Phase 3c: second 64-pt Hadamard
    #pragma unroll
    for (int bit = 1; bit < MD; bit <<= 1) {
        const float o = __shfl_xor(zs, bit, 64);
        zs = (lane & bit) ? (o - zs) : (zs + o);
    }
    const float w = zs * 0.03125f;            // lane L holds w[bin == L]

    // ---- Phase 4: out = x + signs * bpermute(w, inv_perm&63); zero LDS ops
    nfloat4* orow = (nfloat4*)(out + (size_t)r * DIM);
    #pragma unroll
    for (int c = 0; c < 4; ++c) {
        const int4   ip = ((const int4*)inv_perm)[c * 64 + lane];   // L2-hot 4 KB
        const float4 sg = ((const float4*)signs)[c * 64 + lane];
        const float wx = __shfl(w, ip.x & 63, 64);  // ds_bpermute, conflict-free
        const float wy = __shfl(w, ip.y & 63, 64);
        const float wz = __shfl(w, ip.z & 63, 64);
        const float ww = __shfl(w, ip.w & 63, 64);
        nfloat4 o;
        o.x = xs[c].x + sg.x * wx;
        o.y = xs[c].y + sg.y * wy;
        o.z = xs[c].z + sg.z * wz;
        o.w = xs[c].w + sg.w * ww;
        __builtin_nontemporal_store(o, &orow[c * 64 + lane]);
    }
}

extern "C" void kernel_launch(void* const* d_in, const int* in_sizes, int n_in,
                              void* d_out, int out_size, void* d_ws, size_t ws_size,
                              hipStream_t stream) {
    const float* x        = (const float*)d_in[0];
    const float* gates    = (const float*)d_in[1];
    const float* alpha    = (const float*)d_in[2];
    const float* tau      = (const float*)d_in[3];
    const float* signs    = (const float*)d_in[4];
    const int*   perm     = (const int*)d_in[5];
    const int*   inv_perm = (const int*)d_in[6];
    const int*   tgt      = (const int*)d_in[7];
    float*       out      = (float*)d_out;

    const int rows = 4 * SEQ;                 // BSZ * SEQ = 16384
    csa_kernel<<<rows / RPB, WPB * 64, 0, stream>>>(x, gates, alpha, tau, signs,
                                                    perm, inv_perm, tgt, out);
}

// Round 3
// 129.248 us; speedup vs baseline: 1.0323x; 1.0323x over previous
//
#include <hip/hip_runtime.h>

#define SEQ 4096
#define DIM 1024
#define MD 64
#define TOPK 16
#define WPB 2                 // waves per block
#define RPW 2                 // rows per wave (ILP: two independent chains)
#define RPB (WPB * RPW)       // 4 rows per block, 16 KB LDS

typedef float nfloat4 __attribute__((ext_vector_type(4)));  // native vec for nt ld/st

// R8 = R6 dual-row ILP + R7 register-resident epilogue.
//   out[d] = x[d] + signs[d] * w[inv_perm[d] & 63],  w = 1024^-0.5 * H64(zs)
// x stays in registers from phase 1 (no LDS readback); w is one scalar per
// lane so w[bin] is a single ds_bpermute (conflict-free crossbar) indexed by
// the L2-hot inv_perm table. LDS is used ONLY for the phase-2 random gather.
// Per wave-pair epilogue LDS traffic: 0 (R6 had 32 conflicted ds_write_b32 +
// 8 ds_read_b128). RPW=2 keeps two independent latency chains in flight
// through the gather/shuffle/ballot section — dropping it (R7b) cost ~25%.
__global__ __launch_bounds__(WPB * 64) void csa_kernel(
    const float* __restrict__ x,
    const float* __restrict__ gates,
    const float* __restrict__ alpha,
    const float* __restrict__ tau,
    const float* __restrict__ signs,
    const int*   __restrict__ perm,
    const int*   __restrict__ inv_perm,
    const int*   __restrict__ target_idx,
    float*       __restrict__ out)
{
    __shared__ float y[RPB][DIM];

    const int lane = threadIdx.x & 63;
    const int wv   = threadIdx.x >> 6;
    const int r0   = (blockIdx.x * WPB + wv) * RPW;   // first of 2 rows (even)
    const int b    = r0 >> 12;                        // SEQ = 4096; pair shares b

    float* y0 = y[wv * RPW + 0];
    float* y1 = y[wv * RPW + 1];
    const nfloat4* xrow0 = (const nfloat4*)(x + (size_t)(r0 + 0) * DIM);
    const nfloat4* xrow1 = (const nfloat4*)(x + (size_t)(r0 + 1) * DIM);

    // ---- Phase 1: coalesced nt loads; x and signs stay in registers;
    // y = x*signs -> LDS (gather staging only). Rows are wave-private: no
    // barrier needed, only lgkmcnt (compiler-inserted).
    nfloat4 xs0[4], xs1[4];
    float4  sg[4];
    #pragma unroll
    for (int c = 0; c < 4; ++c) {
        sg[c]  = ((const float4*)signs)[c * 64 + lane];
        xs0[c] = __builtin_nontemporal_load(&xrow0[c * 64 + lane]);
        xs1[c] = __builtin_nontemporal_load(&xrow1[c * 64 + lane]);
        float4 a, bq;
        a.x  = xs0[c].x * sg[c].x; a.y  = xs0[c].y * sg[c].y;
        a.z  = xs0[c].z * sg[c].z; a.w  = xs0[c].w * sg[c].w;
        bq.x = xs1[c].x * sg[c].x; bq.y = xs1[c].y * sg[c].y;
        bq.z = xs1[c].z * sg[c].z; bq.w = xs1[c].w * sg[c].w;
        ((float4*)y0)[c * 64 + lane] = a;
        ((float4*)y1)[c * 64 + lane] = bq;
    }

    // ---- Phase 2: fold 1024 -> 64 bins; perm load shared by both rows
    float s0 = 0.f, s1 = 0.f;
    #pragma unroll
    for (int k = 0; k < 16; ++k) {
        const int p = perm[lane + 64 * k];            // coalesced, L1-hot 4 KB
        s0 += y0[p];                                  // random ds_read_b32
        s1 += y1[p];
    }

    // ---- Phase 3a: 64-pt Hadamard, both rows interleaved
    float v0 = s0, v1 = s1;
    #pragma unroll
    for (int bit = 1; bit < MD; bit <<= 1) {
        const float o0 = __shfl_xor(v0, bit, 64);
        const float o1 = __shfl_xor(v1, bit, 64);
        v0 = (lane & bit) ? (o0 - v0) : (v0 + o0);
        v1 = (lane & bit) ? (o1 - v1) : (v1 + o1);
    }

    const int   ti   = target_idx[0];                 // NT == 1
    const float gate = gates[(b + ti) * MD + lane];
    const float tauv = fabsf(tau[b + ti]);
    const float al   = alpha[b + ti];

    const float g0 = gate * v0 * 0.03125f;            // 1024^-0.5
    const float g1 = gate * v1 * 0.03125f;
    const float ag0 = fabsf(g0), ag1 = fabsf(g1);

    // ---- Phase 3b: exact top-16 via bitwise binary search (2 chains);
    // ties -> lowest lane (matches jax.lax.top_k)
    const unsigned ka0 = __float_as_uint(ag0);
    const unsigned ka1 = __float_as_uint(ag1);
    unsigned T0 = 0u, T1 = 0u;
    #pragma unroll
    for (int bit = 30; bit >= 0; --bit) {
        const unsigned c0 = T0 | (1u << bit);
        const unsigned c1 = T1 | (1u << bit);
        if (__popcll(__ballot(ka0 >= c0)) >= TOPK) T0 = c0;
        if (__popcll(__ballot(ka1 >= c1)) >= TOPK) T1 = c1;
    }
    const int ngt0 = __popcll(__ballot(ka0 > T0));
    const int ngt1 = __popcll(__ballot(ka1 > T1));
    const unsigned long long lm = (1ull << lane) - 1ull;
    const int er0 = __popcll(__ballot(ka0 == T0) & lm);
    const int er1 = __popcll(__ballot(ka1 == T1) & lm);
    const bool k0 = (ka0 > T0) || ((ka0 == T0) && (er0 < TOPK - ngt0));
    const bool k1 = (ka1 > T1) || ((ka1 == T1) && (er1 < TOPK - ngt1));

    float zs0 = (k0 && ag0 >= tauv) ? al * g0 : 0.f;
    float zs1 = (k1 && ag1 >= tauv) ? al * g1 : 0.f;

    // ---- Phase 3c: second 64-pt Hadamard, interleaved
    #pragma unroll
    for (int bit = 1; bit < MD; bit <<= 1) {
        const float o0 = __shfl_xor(zs0, bit, 64);
        const float o1 = __shfl_xor(zs1, bit, 64);
        zs0 = (lane & bit) ? (o0 - zs0) : (zs0 + o0);
        zs1 = (lane & bit) ? (o1 - zs1) : (zs1 + o1);
    }
    const float w0 = zs0 * 0.03125f;                  // lane L holds w[bin == L]
    const float w1 = zs1 * 0.03125f;

    // ---- Phase 4: out = x + signs * bpermute(w, inv_perm&63); zero LDS ops
    nfloat4* orow0 = (nfloat4*)(out + (size_t)(r0 + 0) * DIM);
    nfloat4* orow1 = (nfloat4*)(out + (size_t)(r0 + 1) * DIM);
    #pragma unroll
    for (int c = 0; c < 4; ++c) {
        const int4 ip = ((const int4*)inv_perm)[c * 64 + lane];     // L2-hot 4 KB
        const float wx0 = __shfl(w0, ip.x & 63, 64);  // ds_bpermute, no conflicts
        const float wy0 = __shfl(w0, ip.y & 63, 64);
        const float wz0 = __shfl(w0, ip.z & 63, 64);
        const float ww0 = __shfl(w0, ip.w & 63, 64);
        const float wx1 = __shfl(w1, ip.x & 63, 64);
        const float wy1 = __shfl(w1, ip.y & 63, 64);
        const float wz1 = __shfl(w1, ip.z & 63, 64);
        const float ww1 = __shfl(w1, ip.w & 63, 64);
        nfloat4 o0, o1;
        o0.x = xs0[c].x + sg[c].x * wx0;
        o0.y = xs0[c].y + sg[c].y * wy0;
        o0.z = xs0[c].z + sg[c].z * wz0;
        o0.w = xs0[c].w + sg[c].w * ww0;
        o1.x = xs1[c].x + sg[c].x * wx1;
        o1.y = xs1[c].y + sg[c].y * wy1;
        o1.z = xs1[c].z + sg[c].z * wz1;
        o1.w = xs1[c].w + sg[c].w * ww1;
        __builtin_nontemporal_store(o0, &orow0[c * 64 + lane]);
        __builtin_nontemporal_store(o1, &orow1[c * 64 + lane]);
    }
}

extern "C" void kernel_launch(void* const* d_in, const int* in_sizes, int n_in,
                              void* d_out, int out_size, void* d_ws, size_t ws_size,
                              hipStream_t stream) {
    const float* x        = (const float*)d_in[0];
    const float* gates    = (const float*)d_in[1];
    const float* alpha    = (const float*)d_in[2];
    const float* tau      = (const float*)d_in[3];
    const float* signs    = (const float*)d_in[4];
    const int*   perm     = (const int*)d_in[5];
    const int*   inv_perm = (const int*)d_in[6];
    const int*   tgt      = (const int*)d_in[7];
    float*       out      = (float*)d_out;

    const int rows = 4 * SEQ;                         // BSZ * SEQ = 16384
    csa_kernel<<<rows / RPB, WPB * 64, 0, stream>>>(x, gates, alpha, tau, signs,
                                                    perm, inv_perm, tgt, out);
}

// Round 4
// 122.884 us; speedup vs baseline: 1.0857x; 1.0518x over previous
//
#include <hip/hip_runtime.h>

#define SEQ 4096
#define DIM 1024
#define MD 64
#define TOPK 16
#define WPB 2                 // waves per block
#define RPW 2                 // rows per wave (ILP: two independent chains)
#define RPB (WPB * RPW)       // 4 rows per block, 16 KB LDS

typedef float nfloat4 __attribute__((ext_vector_type(4)));  // native vec for nt store

// R9 = R6 structure + conflict-free epilogue with MINIMAL register pressure.
// Identity: signs^2 = 1  =>  out[d] = x[d] + signs[d]*w[inv_perm[d]&63]
//                                   = signs[d]*( y[d] + w[inv_perm[d]&63] )
// and y = x*signs is already in LDS from phase 1 (bit-exact, signs = +-1).
// So the epilogue is: linear ds_read_b128 of y (conflict-free) + L1-hot
// signs/inv_perm reloads + ds_bpermute for w[bin] (conflict-free crossbar).
// vs R6: deletes the 32 random CONFLICTED ds_write_b32 scatter, and drops
// pk[16]/ya[16]/yb[16] (-48 VGPRs; phase 2 is now pure accumulate) so VGPR
// no longer caps occupancy below the 20 waves/CU LDS cap.
// vs R8: x is NOT kept in registers across the mid-section (that was the
// regression: +48 live VGPRs through the latency-bound gather/ballot chain).
__global__ __launch_bounds__(WPB * 64) void csa_kernel(
    const float* __restrict__ x,
    const float* __restrict__ gates,
    const float* __restrict__ alpha,
    const float* __restrict__ tau,
    const float* __restrict__ signs,
    const int*   __restrict__ perm,
    const int*   __restrict__ inv_perm,
    const int*   __restrict__ target_idx,
    float*       __restrict__ out)
{
    __shared__ float y[RPB][DIM];

    const int lane = threadIdx.x & 63;
    const int wv   = threadIdx.x >> 6;
    const int r0   = (blockIdx.x * WPB + wv) * RPW;   // first of 2 rows (even)
    const int b    = r0 >> 12;                        // SEQ = 4096; pair shares b

    float* y0 = y[wv * RPW + 0];
    float* y1 = y[wv * RPW + 1];

    // ---- Phase 1: coalesced loads; y = x*signs -> LDS (x regs then dead).
    // Rows are wave-private: no barrier, only lgkmcnt (compiler-inserted).
    #pragma unroll
    for (int c = 0; c < 4; ++c) {
        const float4 sg = ((const float4*)signs)[c * 64 + lane];
        const float4 xa = ((const float4*)(x + (size_t)(r0 + 0) * DIM))[c * 64 + lane];
        const float4 xb = ((const float4*)(x + (size_t)(r0 + 1) * DIM))[c * 64 + lane];
        float4 a, bq;
        a.x  = xa.x * sg.x; a.y  = xa.y * sg.y; a.z  = xa.z * sg.z; a.w  = xa.w * sg.w;
        bq.x = xb.x * sg.x; bq.y = xb.y * sg.y; bq.z = xb.z * sg.z; bq.w = xb.w * sg.w;
        ((float4*)y0)[c * 64 + lane] = a;
        ((float4*)y1)[c * 64 + lane] = bq;
    }

    // ---- Phase 2: fold 1024 -> 64 bins; pure accumulate (no kept arrays).
    // Element perm[lane + 64k] has bin == lane.
    float s0 = 0.f, s1 = 0.f;
    #pragma unroll
    for (int k = 0; k < 16; ++k) {
        const int p = perm[lane + 64 * k];            // coalesced, L1-hot 4 KB
        s0 += y0[p];                                  // random ds_read_b32
        s1 += y1[p];
    }

    // ---- Phase 3a: 64-pt Hadamard, both rows interleaved
    float v0 = s0, v1 = s1;
    #pragma unroll
    for (int bit = 1; bit < MD; bit <<= 1) {
        const float o0 = __shfl_xor(v0, bit, 64);
        const float o1 = __shfl_xor(v1, bit, 64);
        v0 = (lane & bit) ? (o0 - v0) : (v0 + o0);
        v1 = (lane & bit) ? (o1 - v1) : (v1 + o1);
    }

    const int   ti   = target_idx[0];                 // NT == 1
    const float gate = gates[(b + ti) * MD + lane];
    const float tauv = fabsf(tau[b + ti]);
    const float al   = alpha[b + ti];

    const float g0 = gate * v0 * 0.03125f;            // 1024^-0.5
    const float g1 = gate * v1 * 0.03125f;
    const float ag0 = fabsf(g0), ag1 = fabsf(g1);

    // ---- Phase 3b: exact top-16 via bitwise binary search (2 chains);
    // ties -> lowest lane (matches jax.lax.top_k)
    const unsigned ka0 = __float_as_uint(ag0);
    const unsigned ka1 = __float_as_uint(ag1);
    unsigned T0 = 0u, T1 = 0u;
    #pragma unroll
    for (int bit = 30; bit >= 0; --bit) {
        const unsigned c0 = T0 | (1u << bit);
        const unsigned c1 = T1 | (1u << bit);
        if (__popcll(__ballot(ka0 >= c0)) >= TOPK) T0 = c0;
        if (__popcll(__ballot(ka1 >= c1)) >= TOPK) T1 = c1;
    }
    const int ngt0 = __popcll(__ballot(ka0 > T0));
    const int ngt1 = __popcll(__ballot(ka1 > T1));
    const unsigned long long lm = (1ull << lane) - 1ull;
    const int er0 = __popcll(__ballot(ka0 == T0) & lm);
    const int er1 = __popcll(__ballot(ka1 == T1) & lm);
    const bool k0 = (ka0 > T0) || ((ka0 == T0) && (er0 < TOPK - ngt0));
    const bool k1 = (ka1 > T1) || ((ka1 == T1) && (er1 < TOPK - ngt1));

    float zs0 = (k0 && ag0 >= tauv) ? al * g0 : 0.f;
    float zs1 = (k1 && ag1 >= tauv) ? al * g1 : 0.f;

    // ---- Phase 3c: second 64-pt Hadamard, interleaved
    #pragma unroll
    for (int bit = 1; bit < MD; bit <<= 1) {
        const float o0 = __shfl_xor(zs0, bit, 64);
        const float o1 = __shfl_xor(zs1, bit, 64);
        zs0 = (lane & bit) ? (o0 - zs0) : (zs0 + o0);
        zs1 = (lane & bit) ? (o1 - zs1) : (zs1 + o1);
    }
    const float w0 = zs0 * 0.03125f;                  // lane L holds w[bin == L]
    const float w1 = zs1 * 0.03125f;

    // ---- Phase 4: out = signs * ( y (linear LDS readback) + bpermute(w) ).
    // Zero scattered LDS ops; signs/inv_perm reloads are L1-hot (4 KB each).
    nfloat4* orow0 = (nfloat4*)(out + (size_t)(r0 + 0) * DIM);
    nfloat4* orow1 = (nfloat4*)(out + (size_t)(r0 + 1) * DIM);
    #pragma unroll
    for (int c = 0; c < 4; ++c) {
        const int4   ip = ((const int4*)inv_perm)[c * 64 + lane];
        const float4 sg = ((const float4*)signs)[c * 64 + lane];
        const float4 t0 = ((const float4*)y0)[c * 64 + lane];   // ds_read_b128
        const float4 t1 = ((const float4*)y1)[c * 64 + lane];
        const float wx0 = __shfl(w0, ip.x & 63, 64);  // ds_bpermute, no conflicts
        const float wy0 = __shfl(w0, ip.y & 63, 64);
        const float wz0 = __shfl(w0, ip.z & 63, 64);
        const float ww0 = __shfl(w0, ip.w & 63, 64);
        const float wx1 = __shfl(w1, ip.x & 63, 64);
        const float wy1 = __shfl(w1, ip.y & 63, 64);
        const float wz1 = __shfl(w1, ip.z & 63, 64);
        const float ww1 = __shfl(w1, ip.w & 63, 64);
        nfloat4 o0, o1;
        o0.x = sg.x * (t0.x + wx0);
        o0.y = sg.y * (t0.y + wy0);
        o0.z = sg.z * (t0.z + wz0);
        o0.w = sg.w * (t0.w + ww0);
        o1.x = sg.x * (t1.x + wx1);
        o1.y = sg.y * (t1.y + wy1);
        o1.z = sg.z * (t1.z + wz1);
        o1.w = sg.w * (t1.w + ww1);
        __builtin_nontemporal_store(o0, &orow0[c * 64 + lane]);
        __builtin_nontemporal_store(o1, &orow1[c * 64 + lane]);
    }
}

extern "C" void kernel_launch(void* const* d_in, const int* in_sizes, int n_in,
                              void* d_out, int out_size, void* d_ws, size_t ws_size,
                              hipStream_t stream) {
    const float* x        = (const float*)d_in[0];
    const float* gates    = (const float*)d_in[1];
    const float* alpha    = (const float*)d_in[2];
    const float* tau      = (const float*)d_in[3];
    const float* signs    = (const float*)d_in[4];
    const int*   perm     = (const int*)d_in[5];
    const int*   inv_perm = (const int*)d_in[6];
    const int*   tgt      = (const int*)d_in[7];
    float*       out      = (float*)d_out;

    const int rows = 4 * SEQ;                         // BSZ * SEQ = 16384
    csa_kernel<<<rows / RPB, WPB * 64, 0, stream>>>(x, gates, alpha, tau, signs,
                                                    perm, inv_perm, tgt, out);
}